// Round 13
// baseline (34.933 us; speedup 1.0000x reference)
//
#include <hip/hip_runtime.h>
#include <hip/hip_bf16.h>

typedef __attribute__((ext_vector_type(4))) float f32x4;
typedef __attribute__((ext_vector_type(8))) short s16x8;
typedef __attribute__((ext_vector_type(4))) short s16x4;

#define DHEAD 128
#define KVBLK 64
#define BLKQ 64            // q-rows per block = 4 waves x 16
#define TILEB 16384        // bytes per fragment-ordered 64x128 bf16 tile
#define PAIRB (2 * TILEB)  // K+V pair

__device__ __forceinline__ short f2bf(float x) {
    __hip_bfloat16 h = __float2bfloat16(x);
    return *reinterpret_cast<short*>(&h);
}

// Single fused kernel. Per KV tile, the block stages K and V from f32 global
// into FRAGMENT-ORDERED bf16 LDS (every consume read is base + lane*16
// ds_read_b128, conflict-free — layout identical to R8-R12's prep output):
//   K chunk c (16B): c=(s*4+kk)*64+lane, lane=(g,qi) -> K[16s+qi][kk*32+g*8..+7]
//   V chunk: (dg*2+kk)*64+lane, e<4 -> V[kk*32+g*4+e][dg*16+qi], e>=4 -> +16 rows
// Pipeline: regs hold f32 for tile t+1; convert->LDS buf^1 happens mid-iter t;
// f32 loads for t+2 issued right after (full tile phase of cover). Barrier is
// raw s_barrier + lgkmcnt(0) ONLY — vmcnt never drained, so prefetch loads
// stay in flight across barriers (R5-R7 used __syncthreads whose vmcnt(0)
// drain serialized every tile; R12 proved the counted discipline).
__global__ __launch_bounds__(256, 1)
void attn_fwd(const float* __restrict__ Q, const float* __restrict__ K,
              const float* __restrict__ V, const int* __restrict__ VL,
              float* __restrict__ O, int B, int n, int m) {
    __shared__ char lds[2 * PAIRB];   // 2 x (K | V) = 64 KB

    const int tid  = threadIdx.x;
    const int lane = tid & 63;
    const int wid  = tid >> 6;     // 0..3
    const int g    = lane >> 4;    // 0..3
    const int qi   = lane & 15;

    // XCD-pinned decode (R12): batch b's blocks share one XCD's L2 for K/V.
    const int nq = n / BLKQ;       // 16
    int b, qt;
    if ((B & 7) == 0) {
        const int xcd = blockIdx.x & 7;
        const int sub = blockIdx.x >> 3;
        const int bpx = B >> 3;
        b  = xcd * bpx + (sub % bpx);
        qt = sub / bpx;
    } else {
        b = blockIdx.x / nq; qt = blockIdx.x % nq;
    }

    const int vl = VL[b];
    const int nt = (vl + KVBLK - 1) >> 6;
    const int rowbase = b * n + qt * BLKQ + wid * 16;

    const float* Kb = K + (size_t)b * m * DHEAD;
    const float* Vb = V + (size_t)b * m * DHEAD;

    // ---- Q fragments from f32, pre-scaled by 1/sqrt(d)*log2(e) ----
    const float qsc = 0.08838834764831845f * 1.4426950408889634f;
    s16x8 qf[4];
    {
        const float* qp = Q + ((size_t)rowbase + qi) * DHEAD + g * 8;
        #pragma unroll
        for (int kk = 0; kk < 4; ++kk) {
            f32x4 a  = *reinterpret_cast<const f32x4*>(qp + kk * 32);
            f32x4 cc = *reinterpret_cast<const f32x4*>(qp + kk * 32 + 4);
            s16x8 s;
            #pragma unroll
            for (int j = 0; j < 4; ++j) { s[j] = f2bf(a[j] * qsc); s[4 + j] = f2bf(cc[j] * qsc); }
            qf[kk] = s;
        }
    }

    // ---- staging decode (thread tid handles K chunks tid+256j, V pairs) ----
    // K chunk c: lane_c = c&63 -> (g_c,qi_c); kk_c=(c>>6)&3; s_c=(c>>8)&3
    int krow[4], kcol[4];
    #pragma unroll
    for (int j = 0; j < 4; ++j) {
        const int c  = tid + (j << 8);
        const int lc = c & 63;
        krow[j] = ((c >> 8) & 3) * 16 + (lc & 15);
        kcol[j] = ((c >> 6) & 3) * 32 + (lc >> 4) * 8;
    }
    // V: pass p: rq = (tid>>5)+8p (kv quad 0..15), dq = tid&31 (dv quad)
    const int rq0 = tid >> 5;
    const int dq  = tid & 31;
    // V LDS byte offsets for (rq, dvr=dq*4+jj): ((dg*2+kk)*64 + gw*16 + qiw)*16 + half*8
    int vdst[2][4];
    #pragma unroll
    for (int p = 0; p < 2; ++p) {
        const int rq = rq0 + 8 * p;
        const int kk = rq >> 3, rem = rq & 7;
        const int gw = rem & 3, half = rem >> 2;
        #pragma unroll
        for (int jj = 0; jj < 4; ++jj) {
            const int dvr = dq * 4 + jj;
            vdst[p][jj] = (((dvr >> 4) * 2 + kk) * 64 + gw * 16 + (dvr & 15)) * 16 + half * 8;
        }
    }

    f32x4 kreg[8], vreg[8];
    auto LOADK = [&](int t) {
        const float* Kt = Kb + (size_t)t * KVBLK * DHEAD;
        #pragma unroll
        for (int j = 0; j < 4; ++j) {
            const float* p = Kt + krow[j] * DHEAD + kcol[j];
            kreg[2 * j]     = *reinterpret_cast<const f32x4*>(p);
            kreg[2 * j + 1] = *reinterpret_cast<const f32x4*>(p + 4);
        }
    };
    auto LOADV = [&](int t) {
        const float* Vt = Vb + (size_t)t * KVBLK * DHEAD;
        #pragma unroll
        for (int p = 0; p < 2; ++p)
            #pragma unroll
            for (int r = 0; r < 4; ++r)
                vreg[p * 4 + r] = *reinterpret_cast<const f32x4*>(Vt + ((rq0 + 8 * p) * 4 + r) * DHEAD + dq * 4);
    };
    auto CONV = [&](int buf) {
        char* dst = &lds[buf * PAIRB];
        #pragma unroll
        for (int j = 0; j < 4; ++j) {          // K: linear conflict-free b128 writes
            s16x8 o;
            #pragma unroll
            for (int e = 0; e < 4; ++e) { o[e] = f2bf(kreg[2 * j][e]); o[4 + e] = f2bf(kreg[2 * j + 1][e]); }
            *reinterpret_cast<s16x8*>(dst + (tid + (j << 8)) * 16) = o;
        }
        char* vb = dst + TILEB;
        #pragma unroll
        for (int p = 0; p < 2; ++p)
            #pragma unroll
            for (int jj = 0; jj < 4; ++jj) {   // V: transposed b64 writes
                s16x4 sv;
                sv[0] = f2bf(vreg[p * 4 + 0][jj]); sv[1] = f2bf(vreg[p * 4 + 1][jj]);
                sv[2] = f2bf(vreg[p * 4 + 2][jj]); sv[3] = f2bf(vreg[p * 4 + 3][jj]);
                *reinterpret_cast<s16x4*>(vb + vdst[p][jj]) = sv;
            }
    };

    f32x4 Oacc[8];
    #pragma unroll
    for (int dg = 0; dg < 8; ++dg) Oacc[dg] = 0.f;
    float llocal = 0.f;
    const int lb = lane * 16;

    // ---- prologue: stage tile 0; issue tile 1 loads ----
    LOADK(0); LOADV(0);
    CONV(0);
    if (1 < nt) { LOADK(1); LOADV(1); }
    asm volatile("s_waitcnt lgkmcnt(0)" ::: "memory");
    __builtin_amdgcn_s_barrier();

    int cur = 0;
    #pragma unroll 1
    for (int t = 0; t < nt; ++t) {
        const char* ksb = &lds[cur * PAIRB];
        const char* vsb = ksb + TILEB;

        // ---- S^T = K * Q^T : contiguous b128 fragment reads ----
        f32x4 Sacc[4];
        #pragma unroll
        for (int s = 0; s < 4; ++s) Sacc[s] = 0.f;
        __builtin_amdgcn_s_setprio(1);
        #pragma unroll
        for (int s = 0; s < 4; ++s)
            #pragma unroll
            for (int kk = 0; kk < 4; ++kk) {
                s16x8 kf = *reinterpret_cast<const s16x8*>(ksb + (s * 4 + kk) * 1024 + lb);
                Sacc[s] = __builtin_amdgcn_mfma_f32_16x16x32_bf16(kf, qf[kk], Sacc[s], 0, 0, 0);
            }
        __builtin_amdgcn_s_setprio(0);

        // ---- valid_length mask (tail tile only) ----
        const int kvrem = vl - t * KVBLK;
        if (kvrem < KVBLK) {
            #pragma unroll
            for (int s = 0; s < 4; ++s)
                #pragma unroll
                for (int r = 0; r < 4; ++r)
                    if (s * 16 + g * 4 + r >= kvrem) Sacc[s][r] = -1e30f;
        }

        // ---- fixed-origin softmax numerator; Sacc dies into pa ----
        s16x8 pa[2];
        #pragma unroll
        for (int s = 0; s < 4; ++s)
            #pragma unroll
            for (int r = 0; r < 4; ++r) {
                const float e = __builtin_amdgcn_exp2f(fminf(Sacc[s][r], 60.f));
                llocal += e;
                pa[s >> 1][((s & 1) << 2) + r] = f2bf(e);
            }

        // ---- stage tile t+1 (regs loaded last iter) into buf^1; issue t+2 ----
        if (t + 1 < nt) {
            CONV(cur ^ 1);                       // waits vmcnt for t+1 loads (covered)
            if (t + 2 < nt) { LOADK(t + 2); LOADV(t + 2); }   // in flight across barrier
        }

        // ---- O += P * V : contiguous b128 fragment reads ----
        __builtin_amdgcn_s_setprio(1);
        #pragma unroll
        for (int dg = 0; dg < 8; ++dg)
            #pragma unroll
            for (int kk = 0; kk < 2; ++kk) {
                s16x8 vf = *reinterpret_cast<const s16x8*>(vsb + (dg * 2 + kk) * 1024 + lb);
                Oacc[dg] = __builtin_amdgcn_mfma_f32_16x16x32_bf16(pa[kk], vf, Oacc[dg], 0, 0, 0);
            }
        __builtin_amdgcn_s_setprio(0);

        // ---- rendezvous: LDS ops drained, vmcnt (t+2 loads) NOT drained ----
        asm volatile("s_waitcnt lgkmcnt(0)" ::: "memory");
        __builtin_amdgcn_s_barrier();
        cur ^= 1;
    }

    // ---- l reduction across the 4 replicated groups, normalize, write ----
    llocal += __shfl_xor(llocal, 16);
    llocal += __shfl_xor(llocal, 32);
    const float linv = 1.0f / llocal;
    const float l0 = __shfl(linv, g * 4 + 0);
    const float l1 = __shfl(linv, g * 4 + 1);
    const float l2 = __shfl(linv, g * 4 + 2);
    const float l3 = __shfl(linv, g * 4 + 3);
    float* Ob = O + (size_t)rowbase * DHEAD;
    #pragma unroll
    for (int dg = 0; dg < 8; ++dg) {
        Ob[(g * 4 + 0) * DHEAD + dg * 16 + qi] = Oacc[dg][0] * l0;
        Ob[(g * 4 + 1) * DHEAD + dg * 16 + qi] = Oacc[dg][1] * l1;
        Ob[(g * 4 + 2) * DHEAD + dg * 16 + qi] = Oacc[dg][2] * l2;
        Ob[(g * 4 + 3) * DHEAD + dg * 16 + qi] = Oacc[dg][3] * l3;
    }
}

extern "C" void kernel_launch(void* const* d_in, const int* in_sizes, int n_in,
                              void* d_out, int out_size, void* d_ws, size_t ws_size,
                              hipStream_t stream) {
    const float* Q  = (const float*)d_in[0];
    const float* K  = (const float*)d_in[1];
    const float* V  = (const float*)d_in[2];
    const int*   VL = (const int*)d_in[3];
    float* O = (float*)d_out;

    const int B = in_sizes[3];
    const int n = in_sizes[0] / (B * DHEAD);
    const int m = in_sizes[1] / (B * DHEAD);

    const int grid = B * (n / BLKQ);
    attn_fwd<<<grid, 256, 0, stream>>>(Q, K, V, VL, O, B, n, m);
}

// Round 14
// 34.644 us; speedup vs baseline: 1.0083x; 1.0083x over previous
//
#include <hip/hip_runtime.h>
#include <hip/hip_bf16.h>

typedef __attribute__((ext_vector_type(4))) float f32x4;
typedef __attribute__((ext_vector_type(8))) short s16x8;
typedef unsigned int u32;

#define DHEAD 128
#define KVBLK 64
#define BLKQ 128           // q-rows per block = 8 waves x 16 (halves KV re-read vs 64)
#define TILEB 16384        // bytes per fragment-ordered 64x128 bf16 tile
#define PAIRB (2 * TILEB)  // K+V pair

__device__ __forceinline__ short f2bf(float x) {
    __hip_bfloat16 h = __float2bfloat16(x);
    return *reinterpret_cast<short*>(&h);
}

// Rewrite K,V,Q (f32 row-major) -> bf16 MFMA-FRAGMENT order (identical to R12).
__global__ __launch_bounds__(256)
void prep_frag(const float* __restrict__ K, const float* __restrict__ V,
               const float* __restrict__ Q, const int* __restrict__ VL,
               short* __restrict__ Kz, short* __restrict__ Vz, short* __restrict__ Qz,
               int m, int NT, int nkf, int nqf) {
    const int i = blockIdx.x * 256 + threadIdx.x;
    const float qsc = 0.08838834764831845f * 1.4426950408889634f;
    if (i < nkf) {
        const int lane = i & 63;
        const int kk   = (i >> 6) & 3;
        const int s    = (i >> 8) & 3;
        const int rest = i >> 10;
        const int t = rest % NT, b = rest / NT;
        if (t * KVBLK >= VL[b]) return;
        const int qi = lane & 15, g = lane >> 4;
        const float* src = K + (size_t)(b * m + t * KVBLK + 16 * s + qi) * DHEAD + kk * 32 + g * 8;
        f32x4 a = *reinterpret_cast<const f32x4*>(src);
        f32x4 c = *reinterpret_cast<const f32x4*>(src + 4);
        s16x8 o;
        #pragma unroll
        for (int j = 0; j < 4; ++j) { o[j] = f2bf(a[j]); o[4 + j] = f2bf(c[j]); }
        *reinterpret_cast<s16x8*>(Kz + (size_t)i * 8) = o;
    } else if (i < 2 * nkf) {
        const int j = i - nkf;
        const int lane = j & 63;
        const int kk   = (j >> 6) & 1;
        const int dg   = (j >> 7) & 7;
        const int rest = j >> 10;
        const int t = rest % NT, b = rest / NT;
        if (t * KVBLK >= VL[b]) return;
        const int qi = lane & 15, g = lane >> 4;
        const float* vb = V + (size_t)(b * m + t * KVBLK + kk * 32 + g * 4) * DHEAD + dg * 16 + qi;
        s16x8 o;
        #pragma unroll
        for (int r = 0; r < 4; ++r) {
            o[r]     = f2bf(vb[(size_t)r * DHEAD]);
            o[4 + r] = f2bf(vb[(size_t)(16 + r) * DHEAD]);
        }
        *reinterpret_cast<s16x8*>(Vz + (size_t)j * 8) = o;
    } else {
        const int j = i - 2 * nkf;
        if (j < nqf) {
            const int lane = j & 63;
            const int kk   = (j >> 6) & 3;
            const int grp  = j >> 8;
            const int qi = lane & 15, g = lane >> 4;
            const float* src = Q + ((size_t)grp * 16 + qi) * DHEAD + kk * 32 + g * 8;
            f32x4 a = *reinterpret_cast<const f32x4*>(src);
            f32x4 c = *reinterpret_cast<const f32x4*>(src + 4);
            s16x8 o;
            #pragma unroll
            for (int e = 0; e < 4; ++e) { o[e] = f2bf(a[e] * qsc); o[4 + e] = f2bf(c[e] * qsc); }
            *reinterpret_cast<s16x8*>(Qz + (size_t)j * 8) = o;
        }
    }
}

// Flash attention, fixed-origin softmax. R12's pipeline (3 LDS buffers,
// depth-2 prefetch, counted vmcnt + raw s_barrier, S=1) at BLKQ=128:
// R13's counters showed the true bottleneck is AGGREGATE K/V re-read traffic
// (~16 MB/tile-phase chip-wide from L3 = the ~2.6us/tile invariant). bf16
// tiles (prep) + 128-row q-blocks cut it 4x vs R13, and XCD-pinned decode
// makes each XCD's ~2 MB working set L2-resident.
__global__ __launch_bounds__(512, 1)
void attn_fwd(const short* __restrict__ Qz, const short* __restrict__ Kz,
              const short* __restrict__ Vz, const int* __restrict__ VL,
              float* __restrict__ O, int B, int n, int NT) {
    __shared__ char lds[3 * PAIRB];   // 3 x (K | V) = 96 KB

    const int tid  = threadIdx.x;
    const int lane = tid & 63;
    const int wid  = tid >> 6;     // 0..7
    const int g    = lane >> 4;    // 0..3
    const int qi   = lane & 15;

    // XCD-pinned decode: 2 batches per XCD -> bf16 K/V working set ~2MB < 4MB L2.
    const int nq = n / BLKQ;       // 8
    int b, qt;
    if ((B & 7) == 0) {
        const int xcd = blockIdx.x & 7;
        const int sub = blockIdx.x >> 3;
        const int bpx = B >> 3;
        b  = xcd * bpx + (sub % bpx);
        qt = sub / bpx;
    } else {
        b = blockIdx.x / nq; qt = blockIdx.x % nq;
    }

    const int vl = VL[b];
    const int nt = (vl + KVBLK - 1) >> 6;
    const int rowbase = b * n + qt * BLKQ + wid * 16;

    // ---- Q fragments: 4 linear bf16 loads (pre-scaled in prep) ----
    s16x8 qf[4];
    {
        const char* qg = (const char*)Qz + (size_t)(rowbase >> 4) * 4096 + lane * 16;
        #pragma unroll
        for (int kk = 0; kk < 4; ++kk)
            qf[kk] = *reinterpret_cast<const s16x8*>(qg + kk * 1024);
    }

    const char* KzB = (const char*)Kz + (size_t)b * NT * TILEB;
    const char* VzB = (const char*)Vz + (size_t)b * NT * TILEB;

    // DMA tile pair: 4 x global_load_lds(16B) per wave (2KB K + 2KB V each).
    auto DMA = [&](int buf, int t) {
        const char* ks = KzB + (size_t)t * TILEB;
        const char* vs = VzB + (size_t)t * TILEB;
        char* dst = &lds[buf * PAIRB];
        #pragma unroll
        for (int j = 0; j < 2; ++j) {
            const int off = wid * 2048 + j * 1024;
            __builtin_amdgcn_global_load_lds(
                (const __attribute__((address_space(1))) u32*)(ks + off + lane * 16),
                (__attribute__((address_space(3))) u32*)(dst + off), 16, 0, 0);
            __builtin_amdgcn_global_load_lds(
                (const __attribute__((address_space(1))) u32*)(vs + off + lane * 16),
                (__attribute__((address_space(3))) u32*)(dst + TILEB + off), 16, 0, 0);
        }
    };

    f32x4 Oacc[8];
    #pragma unroll
    for (int dg = 0; dg < 8; ++dg) Oacc[dg] = 0.f;
    float llocal = 0.f;
    const int lb = lane * 16;

    // ---- prologue: fill pipeline 2 deep ----
    DMA(0, 0);
    if (1 < nt) DMA(1, 1);

    int cur = 0;
    #pragma unroll 1
    for (int t = 0; t < nt; ++t) {
        // wait ONLY for tile t's 4 loads; tile t+1's stay in flight
        if (t + 1 < nt) { asm volatile("s_waitcnt vmcnt(4)" ::: "memory"); }
        else            { asm volatile("s_waitcnt vmcnt(0)" ::: "memory"); }
        __builtin_amdgcn_s_barrier();   // tile t visible to all waves; prev readers done

        // issue tile t+2 into the buffer freed by iter t-1
        if (t + 2 < nt) {
            int nb = cur + 2; if (nb >= 3) nb -= 3;
            DMA(nb, t + 2);
        }

        const char* ksb = &lds[cur * PAIRB];
        const char* vsb = ksb + TILEB;

        // ---- S^T = K * Q^T : contiguous b128 fragment reads ----
        f32x4 Sacc[4];
        #pragma unroll
        for (int s = 0; s < 4; ++s) Sacc[s] = 0.f;
        __builtin_amdgcn_s_setprio(1);
        #pragma unroll
        for (int s = 0; s < 4; ++s)
            #pragma unroll
            for (int kk = 0; kk < 4; ++kk) {
                s16x8 kf = *reinterpret_cast<const s16x8*>(ksb + (s * 4 + kk) * 1024 + lb);
                Sacc[s] = __builtin_amdgcn_mfma_f32_16x16x32_bf16(kf, qf[kk], Sacc[s], 0, 0, 0);
            }
        __builtin_amdgcn_s_setprio(0);

        // ---- valid_length mask (tail tile only) ----
        const int kvrem = vl - t * KVBLK;
        if (kvrem < KVBLK) {
            #pragma unroll
            for (int s = 0; s < 4; ++s)
                #pragma unroll
                for (int r = 0; r < 4; ++r)
                    if (s * 16 + g * 4 + r >= kvrem) Sacc[s][r] = -1e30f;
        }

        // ---- fixed-origin softmax numerator; Sacc dies into pa ----
        s16x8 pa[2];
        #pragma unroll
        for (int s = 0; s < 4; ++s)
            #pragma unroll
            for (int r = 0; r < 4; ++r) {
                const float e = __builtin_amdgcn_exp2f(fminf(Sacc[s][r], 60.f));
                llocal += e;
                pa[s >> 1][((s & 1) << 2) + r] = f2bf(e);
            }

        // ---- O += P * V : contiguous b128 fragment reads ----
        __builtin_amdgcn_s_setprio(1);
        #pragma unroll
        for (int dg = 0; dg < 8; ++dg)
            #pragma unroll
            for (int kk = 0; kk < 2; ++kk) {
                s16x8 vf = *reinterpret_cast<const s16x8*>(vsb + (dg * 2 + kk) * 1024 + lb);
                Oacc[dg] = __builtin_amdgcn_mfma_f32_16x16x32_bf16(pa[kk], vf, Oacc[dg], 0, 0, 0);
            }
        __builtin_amdgcn_s_setprio(0);

        cur += 1; if (cur >= 3) cur -= 3;
        // no trailing drain: next iter's counted vmcnt + barrier is the rendezvous
    }

    // ---- l reduction across the 4 replicated groups, normalize, write ----
    llocal += __shfl_xor(llocal, 16);
    llocal += __shfl_xor(llocal, 32);
    const float linv = 1.0f / llocal;
    const float l0 = __shfl(linv, g * 4 + 0);
    const float l1 = __shfl(linv, g * 4 + 1);
    const float l2 = __shfl(linv, g * 4 + 2);
    const float l3 = __shfl(linv, g * 4 + 3);
    float* Ob = O + (size_t)rowbase * DHEAD;
    #pragma unroll
    for (int dg = 0; dg < 8; ++dg) {
        Ob[(g * 4 + 0) * DHEAD + dg * 16 + qi] = Oacc[dg][0] * l0;
        Ob[(g * 4 + 1) * DHEAD + dg * 16 + qi] = Oacc[dg][1] * l1;
        Ob[(g * 4 + 2) * DHEAD + dg * 16 + qi] = Oacc[dg][2] * l2;
        Ob[(g * 4 + 3) * DHEAD + dg * 16 + qi] = Oacc[dg][3] * l3;
    }
}

extern "C" void kernel_launch(void* const* d_in, const int* in_sizes, int n_in,
                              void* d_out, int out_size, void* d_ws, size_t ws_size,
                              hipStream_t stream) {
    const float* Q  = (const float*)d_in[0];
    const float* K  = (const float*)d_in[1];
    const float* V  = (const float*)d_in[2];
    const int*   VL = (const int*)d_in[3];
    float* O = (float*)d_out;

    const int B = in_sizes[3];
    const int n = in_sizes[0] / (B * DHEAD);
    const int m = in_sizes[1] / (B * DHEAD);
    const int rows = B * n;
    const int NT = m / KVBLK;

    short* Kz = (short*)d_ws;
    short* Vz = Kz + (size_t)B * NT * (TILEB / 2);
    short* Qz = Vz + (size_t)B * NT * (TILEB / 2);

    const int nkf = B * NT * 1024;           // s16x8 units per K (and V) tensor
    const int nqf = (rows / 16) * 256;       // s16x8 units for Q
    prep_frag<<<(2 * nkf + nqf + 255) / 256, 256, 0, stream>>>(K, V, Q, VL, Kz, Vz, Qz, m, NT, nkf, nqf);

    const int grid = B * (n / BLKQ);
    attn_fwd<<<grid, 512, 0, stream>>>(Qz, Kz, Vz, VL, O, B, n, NT);
}

// Round 15
// 32.403 us; speedup vs baseline: 1.0781x; 1.0691x over previous
//
#include <hip/hip_runtime.h>
#include <hip/hip_bf16.h>

typedef __attribute__((ext_vector_type(4))) float f32x4;
typedef __attribute__((ext_vector_type(8))) short s16x8;
typedef unsigned int u32;

#define DHEAD 128
#define KVBLK 64
#define BLKQ 64            // q-rows per block = 4 waves x 16
#define TILEB 16384        // bytes per fragment-ordered 64x128 bf16 tile
#define PAIRB (2 * TILEB)  // K+V pair (32 KB)

__device__ __forceinline__ short f2bf(float x) {
    __hip_bfloat16 h = __float2bfloat16(x);
    return *reinterpret_cast<short*>(&h);
}
__device__ __forceinline__ float bf2f(short s) {
    __hip_bfloat16 h = *reinterpret_cast<__hip_bfloat16*>(&s);
    return __bfloat162float(h);
}

// Rewrite K,V,Q (f32 row-major) -> bf16 MFMA-FRAGMENT order (identical to R12).
__global__ __launch_bounds__(256)
void prep_frag(const float* __restrict__ K, const float* __restrict__ V,
               const float* __restrict__ Q, const int* __restrict__ VL,
               short* __restrict__ Kz, short* __restrict__ Vz, short* __restrict__ Qz,
               int m, int NT, int nkf, int nqf) {
    const int i = blockIdx.x * 256 + threadIdx.x;
    const float qsc = 0.08838834764831845f * 1.4426950408889634f;
    if (i < nkf) {
        const int lane = i & 63;
        const int kk   = (i >> 6) & 3;
        const int s    = (i >> 8) & 3;
        const int rest = i >> 10;
        const int t = rest % NT, b = rest / NT;
        if (t * KVBLK >= VL[b]) return;
        const int qi = lane & 15, g = lane >> 4;
        const float* src = K + (size_t)(b * m + t * KVBLK + 16 * s + qi) * DHEAD + kk * 32 + g * 8;
        f32x4 a = *reinterpret_cast<const f32x4*>(src);
        f32x4 c = *reinterpret_cast<const f32x4*>(src + 4);
        s16x8 o;
        #pragma unroll
        for (int j = 0; j < 4; ++j) { o[j] = f2bf(a[j]); o[4 + j] = f2bf(c[j]); }
        *reinterpret_cast<s16x8*>(Kz + (size_t)i * 8) = o;
    } else if (i < 2 * nkf) {
        const int j = i - nkf;
        const int lane = j & 63;
        const int kk   = (j >> 6) & 1;
        const int dg   = (j >> 7) & 7;
        const int rest = j >> 10;
        const int t = rest % NT, b = rest / NT;
        if (t * KVBLK >= VL[b]) return;
        const int qi = lane & 15, g = lane >> 4;
        const float* vb = V + (size_t)(b * m + t * KVBLK + kk * 32 + g * 4) * DHEAD + dg * 16 + qi;
        s16x8 o;
        #pragma unroll
        for (int r = 0; r < 4; ++r) {
            o[r]     = f2bf(vb[(size_t)r * DHEAD]);
            o[4 + r] = f2bf(vb[(size_t)(16 + r) * DHEAD]);
        }
        *reinterpret_cast<s16x8*>(Vz + (size_t)j * 8) = o;
    } else {
        const int j = i - 2 * nkf;
        if (j < nqf) {
            const int lane = j & 63;
            const int kk   = (j >> 6) & 3;
            const int grp  = j >> 8;
            const int qi = lane & 15, g = lane >> 4;
            const float* src = Q + ((size_t)grp * 16 + qi) * DHEAD + kk * 32 + g * 8;
            f32x4 a = *reinterpret_cast<const f32x4*>(src);
            f32x4 c = *reinterpret_cast<const f32x4*>(src + 4);
            s16x8 o;
            #pragma unroll
            for (int e = 0; e < 4; ++e) { o[e] = f2bf(a[e] * qsc); o[4 + e] = f2bf(c[e] * qsc); }
            *reinterpret_cast<s16x8*>(Qz + (size_t)j * 8) = o;
        }
    }
}

// Flash attention, fixed-origin softmax. R12 data path at 2 blocks/CU:
// 4 waves x 16 q-rows, KVBLK=64, TWO LDS buffers (64 KB -> 2 blocks/CU,
// 2 waves/SIMD), cyclic kv-split S=2 (grid 512), T3 2-phase loop:
// stage(next,buf^1) -> compute(buf) -> syncthreads (drain covered by compute).
// R12's 1 wave/SIMD left intra-tile latency (ds_read->MFMA chains, softmax
// serial adds, barrier spread) unhidden (R13 PMC: VALUBusy 6.5%, 93% stalled);
// the co-resident sibling block fills those slots. XCD-pinned decode keeps
// each XCD's bf16 KV working set (~2 batches ~2 MB) L2-resident.
__global__ __launch_bounds__(256, 2)
void attn_fwd(const short* __restrict__ Qz, const short* __restrict__ Kz,
              const short* __restrict__ Vz, const int* __restrict__ VL,
              float* __restrict__ O, short* __restrict__ OPb, float* __restrict__ Lp,
              int B, int n, int NT, int S, int rows) {
    __shared__ char lds[2 * PAIRB];   // 2 x (K | V) = 64 KB

    const int tid  = threadIdx.x;
    const int lane = tid & 63;
    const int wid  = tid >> 6;     // 0..3
    const int g    = lane >> 4;    // 0..3
    const int qi   = lane & 15;

    const int nq = n / BLKQ;       // 16
    int b, rest;
    if ((B & 7) == 0) {
        const int xcd = blockIdx.x & 7;
        const int sub = blockIdx.x >> 3;
        const int bpx = B >> 3;
        b    = xcd * bpx + (sub % bpx);
        rest = sub / bpx;          // 0 .. nq*S-1
    } else {
        const int per = nq * S;
        b    = blockIdx.x / per;
        rest = blockIdx.x % per;
    }
    const int qt = rest / S;
    const int c  = rest % S;

    const int vl = VL[b];
    const int nt = (vl + KVBLK - 1) >> 6;
    const int rowbase = b * n + qt * BLKQ + wid * 16;

    if (c >= nt) {   // empty chunk (cyclic: chunk c owns tiles c, c+S, ...)
        if (S > 1 && g == 0) Lp[(size_t)c * rows + rowbase + qi] = 0.f;
        return;
    }
    const int cnt = (nt - c + S - 1) / S;

    // ---- Q fragments: 4 linear bf16 loads (pre-scaled in prep) ----
    s16x8 qf[4];
    {
        const char* qg = (const char*)Qz + (size_t)(rowbase >> 4) * 4096 + lane * 16;
        #pragma unroll
        for (int kk = 0; kk < 4; ++kk)
            qf[kk] = *reinterpret_cast<const s16x8*>(qg + kk * 1024);
    }

    const char* KzB = (const char*)Kz + (size_t)b * NT * TILEB;
    const char* VzB = (const char*)Vz + (size_t)b * NT * TILEB;

    // DMA tile pair: 8 x global_load_lds(16B) per wave (4KB K + 4KB V each).
    auto DMA = [&](int buf, int t) {
        const char* ks = KzB + (size_t)t * TILEB;
        const char* vs = VzB + (size_t)t * TILEB;
        char* dst = &lds[buf * PAIRB];
        #pragma unroll
        for (int j = 0; j < 4; ++j) {
            const int off = wid * 4096 + j * 1024;
            __builtin_amdgcn_global_load_lds(
                (const __attribute__((address_space(1))) u32*)(ks + off + lane * 16),
                (__attribute__((address_space(3))) u32*)(dst + off), 16, 0, 0);
            __builtin_amdgcn_global_load_lds(
                (const __attribute__((address_space(1))) u32*)(vs + off + lane * 16),
                (__attribute__((address_space(3))) u32*)(dst + TILEB + off), 16, 0, 0);
        }
    };

    f32x4 Oacc[8];
    #pragma unroll
    for (int dg = 0; dg < 8; ++dg) Oacc[dg] = 0.f;
    float llocal = 0.f;
    const int lb = lane * 16;

    // ---- prologue: stage first tile ----
    DMA(0, c);
    __syncthreads();

    int cur = 0;
    #pragma unroll 1
    for (int i = 0; i < cnt; ++i) {
        const int t = c + i * S;

        // ---- T3: issue next tile's DMA into buf^1 (drained at end-of-iter sync,
        //      with the whole compute phase as latency cover) ----
        if (i + 1 < cnt) DMA(cur ^ 1, t + S);

        const char* ksb = &lds[cur * PAIRB];
        const char* vsb = ksb + TILEB;

        // ---- S^T = K * Q^T : contiguous b128 fragment reads ----
        f32x4 Sacc[4];
        #pragma unroll
        for (int s = 0; s < 4; ++s) Sacc[s] = 0.f;
        __builtin_amdgcn_s_setprio(1);
        #pragma unroll
        for (int s = 0; s < 4; ++s)
            #pragma unroll
            for (int kk = 0; kk < 4; ++kk) {
                s16x8 kf = *reinterpret_cast<const s16x8*>(ksb + (s * 4 + kk) * 1024 + lb);
                Sacc[s] = __builtin_amdgcn_mfma_f32_16x16x32_bf16(kf, qf[kk], Sacc[s], 0, 0, 0);
            }
        __builtin_amdgcn_s_setprio(0);

        // ---- valid_length mask (tail tile only) ----
        const int kvrem = vl - t * KVBLK;
        if (kvrem < KVBLK) {
            #pragma unroll
            for (int s = 0; s < 4; ++s)
                #pragma unroll
                for (int r = 0; r < 4; ++r)
                    if (s * 16 + g * 4 + r >= kvrem) Sacc[s][r] = -1e30f;
        }

        // ---- fixed-origin softmax numerator; Sacc dies into pa ----
        s16x8 pa[2];
        #pragma unroll
        for (int s = 0; s < 4; ++s)
            #pragma unroll
            for (int r = 0; r < 4; ++r) {
                const float e = __builtin_amdgcn_exp2f(fminf(Sacc[s][r], 60.f));
                llocal += e;
                pa[s >> 1][((s & 1) << 2) + r] = f2bf(e);
            }

        // ---- O += P * V : contiguous b128 fragment reads ----
        __builtin_amdgcn_s_setprio(1);
        #pragma unroll
        for (int dg = 0; dg < 8; ++dg)
            #pragma unroll
            for (int kk = 0; kk < 2; ++kk) {
                s16x8 vf = *reinterpret_cast<const s16x8*>(vsb + (dg * 2 + kk) * 1024 + lb);
                Oacc[dg] = __builtin_amdgcn_mfma_f32_16x16x32_bf16(pa[kk], vf, Oacc[dg], 0, 0, 0);
            }
        __builtin_amdgcn_s_setprio(0);

        __syncthreads();   // next tile's DMA drained (covered); buf free
        cur ^= 1;
    }

    // ---- one-time l reduction across the 4 replicated groups ----
    llocal += __shfl_xor(llocal, 16);
    llocal += __shfl_xor(llocal, 32);

    if (S > 1) {
        if (g == 0) Lp[(size_t)c * rows + rowbase + qi] = llocal;
        short* Op = OPb + ((size_t)c * rows + rowbase) * DHEAD;
        #pragma unroll
        for (int dg = 0; dg < 8; ++dg) {
            Op[(g * 4 + 0) * DHEAD + dg * 16 + qi] = f2bf(Oacc[dg][0]);
            Op[(g * 4 + 1) * DHEAD + dg * 16 + qi] = f2bf(Oacc[dg][1]);
            Op[(g * 4 + 2) * DHEAD + dg * 16 + qi] = f2bf(Oacc[dg][2]);
            Op[(g * 4 + 3) * DHEAD + dg * 16 + qi] = f2bf(Oacc[dg][3]);
        }
    } else {
        const float linv = 1.0f / llocal;
        const float l0 = __shfl(linv, g * 4 + 0);
        const float l1 = __shfl(linv, g * 4 + 1);
        const float l2 = __shfl(linv, g * 4 + 2);
        const float l3 = __shfl(linv, g * 4 + 3);
        float* Ob = O + (size_t)rowbase * DHEAD;
        #pragma unroll
        for (int dg = 0; dg < 8; ++dg) {
            Ob[(g * 4 + 0) * DHEAD + dg * 16 + qi] = Oacc[dg][0] * l0;
            Ob[(g * 4 + 1) * DHEAD + dg * 16 + qi] = Oacc[dg][1] * l1;
            Ob[(g * 4 + 2) * DHEAD + dg * 16 + qi] = Oacc[dg][2] * l2;
            Ob[(g * 4 + 3) * DHEAD + dg * 16 + qi] = Oacc[dg][3] * l3;
        }
    }
}

// merge: all chunks share origin m=0, so O = (sum_s OP_s) / (sum_s l_s)
__global__ __launch_bounds__(128)
void attn_combine(const short* __restrict__ OPb, const float* __restrict__ Lp,
                  float* __restrict__ O, int S, int rows) {
    const int row = blockIdx.x;
    const int t   = threadIdx.x;
    float L = 0.f, acc = 0.f;
    for (int s = 0; s < S; ++s) {
        const float ls = Lp[(size_t)s * rows + row];
        if (ls > 0.f) {
            L += ls;
            acc += bf2f(OPb[((size_t)s * rows + row) * DHEAD + t]);
        }
    }
    O[(size_t)row * DHEAD + t] = acc / L;
}

extern "C" void kernel_launch(void* const* d_in, const int* in_sizes, int n_in,
                              void* d_out, int out_size, void* d_ws, size_t ws_size,
                              hipStream_t stream) {
    const float* Q  = (const float*)d_in[0];
    const float* K  = (const float*)d_in[1];
    const float* V  = (const float*)d_in[2];
    const int*   VL = (const int*)d_in[3];
    float* O = (float*)d_out;

    const int B = in_sizes[3];
    const int n = in_sizes[0] / (B * DHEAD);
    const int m = in_sizes[1] / (B * DHEAD);
    const int rows = B * n;
    const int NT = m / KVBLK;

    short* Kz = (short*)d_ws;
    short* Vz = Kz + (size_t)B * NT * (TILEB / 2);
    short* Qz = Vz + (size_t)B * NT * (TILEB / 2);
    const size_t used = 2 * (size_t)B * NT * TILEB + (size_t)rows * DHEAD * 2;  // ~12.6 MB

    const size_t per_chunk = (size_t)rows * (DHEAD * 2 + 4);
    const int S = (ws_size >= used + 2 * per_chunk) ? 2 : 1;

    short* OPb = (short*)((char*)d_ws + used);
    float* Lp  = (float*)((char*)d_ws + used + (size_t)S * rows * DHEAD * 2);

    const int nkf = B * NT * 1024;           // s16x8 units per K (and V) tensor
    const int nqf = (rows / 16) * 256;       // s16x8 units for Q
    prep_frag<<<(2 * nkf + nqf + 255) / 256, 256, 0, stream>>>(K, V, Q, VL, Kz, Vz, Qz, m, NT, nkf, nqf);

    const int grid = B * (n / BLKQ) * S;
    attn_fwd<<<grid, 256, 0, stream>>>(Qz, Kz, Vz, VL, O, OPb, Lp, B, n, NT, S, rows);
    if (S > 1)
        attn_combine<<<rows, 128, 0, stream>>>(OPb, Lp, O, S, rows);
}

// Round 16
// 26.560 us; speedup vs baseline: 1.3152x; 1.2200x over previous
//
#include <hip/hip_runtime.h>
#include <hip/hip_bf16.h>

typedef __attribute__((ext_vector_type(4))) float f32x4;
typedef __attribute__((ext_vector_type(8))) short s16x8;
typedef unsigned int u32;

#define DHEAD 128
#define KVB 32             // kv rows per tile
#define BLKQ 64            // q-rows per block = 4 q-slots x 16
#define NGRP 4             // in-block kv groups (4 waves each)
#define TILB 8192          // bytes per fragment-ordered 32x128 bf16 tile
#define LDSZ 131072        // 4 groups x 2 bufs x (8KB K + 8KB V)

__device__ __forceinline__ short f2bf(float x) {
    __hip_bfloat16 h = __float2bfloat16(x);
    return *reinterpret_cast<short*>(&h);
}

// Rewrite K,V (f32 row-major) -> bf16 MFMA-FRAGMENT order, 32-row tiles:
//  K tile t: unit u=(s*4+kk)*64+lane, lane=(g,qi): K[t*32+16s+qi][kk*32+g*8+e]
//  V tile t: unit u=dg*64+lane: e<4: V[t*32+g*4+e][dg*16+qi]; e>=4: +16 rows
__global__ __launch_bounds__(256)
void prep_frag(const float* __restrict__ K, const float* __restrict__ V,
               const int* __restrict__ VL,
               short* __restrict__ Kz, short* __restrict__ Vz, int m, int NT, int nkf) {
    const int i = blockIdx.x * 256 + threadIdx.x;
    if (i < nkf) {
        const int lane = i & 63;
        const int kk   = (i >> 6) & 3;
        const int s    = (i >> 8) & 1;
        const int rest = i >> 9;
        const int t = rest % NT, b = rest / NT;
        if (t * KVB >= VL[b]) return;
        const int qi = lane & 15, g = lane >> 4;
        const float* src = K + (size_t)(b * m + t * KVB + 16 * s + qi) * DHEAD + kk * 32 + g * 8;
        f32x4 a = *reinterpret_cast<const f32x4*>(src);
        f32x4 c = *reinterpret_cast<const f32x4*>(src + 4);
        s16x8 o;
        #pragma unroll
        for (int j = 0; j < 4; ++j) { o[j] = f2bf(a[j]); o[4 + j] = f2bf(c[j]); }
        *reinterpret_cast<s16x8*>(Kz + (size_t)i * 8) = o;
    } else {
        const int j = i - nkf;
        if (j < nkf) {
            const int lane = j & 63;
            const int dg   = (j >> 6) & 7;
            const int rest = j >> 9;
            const int t = rest % NT, b = rest / NT;
            if (t * KVB >= VL[b]) return;
            const int qi = lane & 15, g = lane >> 4;
            const float* vb = V + (size_t)(b * m + t * KVB + g * 4) * DHEAD + dg * 16 + qi;
            s16x8 o;
            #pragma unroll
            for (int r = 0; r < 4; ++r) {
                o[r]     = f2bf(vb[(size_t)r * DHEAD]);
                o[4 + r] = f2bf(vb[(size_t)(16 + r) * DHEAD]);
            }
            *reinterpret_cast<s16x8*>(Vz + (size_t)j * 8) = o;
        }
    }
}

// Flash attention, fixed-origin softmax, IN-BLOCK kv-split:
// 16 waves = 4 q-slots x 4 kv-groups; group g owns tiles t = g (mod 4), with a
// group-private double-buffered LDS pipeline (T3 2-phase). Each SIMD hosts 4
// waves from 4 DIFFERENT groups -> independent work hides all stalls. Uniform
// iteration count keeps s_barrier legal. Final merge is an in-LDS sum (fixed
// origin => associative), no workspace partials, no combine kernel.
__global__ __launch_bounds__(1024, 4)
void attn_fwd(const float* __restrict__ Q, const short* __restrict__ Kz,
              const short* __restrict__ Vz, const int* __restrict__ VL,
              float* __restrict__ O, int B, int n, int NT) {
    extern __shared__ char lds[];   // LDSZ bytes

    const int tid   = threadIdx.x;
    const int lane  = tid & 63;
    const int wid   = tid >> 6;     // 0..15
    const int qslot = wid & 3;      // q sub-tile (16 rows)
    const int grp   = wid >> 2;     // kv group 0..3
    const int gl    = lane >> 4;    // 0..3
    const int qi    = lane & 15;

    // XCD-pinned decode: 2 batches/XCD -> bf16 KV stream L2-resident.
    const int nq = n / BLKQ;        // 16
    int b, qt;
    if ((B & 7) == 0) {
        const int xcd = blockIdx.x & 7;
        const int sub = blockIdx.x >> 3;
        const int bpx = B >> 3;
        b  = xcd * bpx + (sub % bpx);
        qt = sub / bpx;
    } else {
        b = blockIdx.x / nq; qt = blockIdx.x % nq;
    }

    const int vl = VL[b];
    const int nt = (vl + KVB - 1) / KVB;        // tiles in 32-units (1..32)
    const int IT = (nt + NGRP - 1) / NGRP;      // uniform per-group iterations
    const int rowbase = b * n + qt * BLKQ + qslot * 16;

    // ---- Q fragments from f32, pre-scaled by 1/sqrt(d)*log2(e) ----
    const float qsc = 0.08838834764831845f * 1.4426950408889634f;
    s16x8 qf[4];
    {
        const float* qp = Q + (size_t)(rowbase + qi) * DHEAD + gl * 8;
        #pragma unroll
        for (int kk = 0; kk < 4; ++kk) {
            f32x4 a  = *reinterpret_cast<const f32x4*>(qp + kk * 32);
            f32x4 cc = *reinterpret_cast<const f32x4*>(qp + kk * 32 + 4);
            s16x8 s;
            #pragma unroll
            for (int j = 0; j < 4; ++j) { s[j] = f2bf(a[j] * qsc); s[4 + j] = f2bf(cc[j] * qsc); }
            qf[kk] = s;
        }
    }

    const char* KzB = (const char*)Kz + (size_t)b * NT * TILB;
    const char* VzB = (const char*)Vz + (size_t)b * NT * TILB;

    // group-private DMA: this wave stages 2KB of K + 2KB of V of its group's tile
    auto DMA = [&](int buf, int t) {
        const char* ks = KzB + (size_t)t * TILB;
        const char* vs = VzB + (size_t)t * TILB;
        char* dst = &lds[grp * 32768 + buf * 16384];
        const int off = qslot * 2048;
        #pragma unroll
        for (int j = 0; j < 2; ++j) {
            __builtin_amdgcn_global_load_lds(
                (const __attribute__((address_space(1))) u32*)(ks + off + j * 1024 + lane * 16),
                (__attribute__((address_space(3))) u32*)(dst + off + j * 1024), 16, 0, 0);
            __builtin_amdgcn_global_load_lds(
                (const __attribute__((address_space(1))) u32*)(vs + off + j * 1024 + lane * 16),
                (__attribute__((address_space(3))) u32*)(dst + 8192 + off + j * 1024), 16, 0, 0);
        }
    };

    f32x4 Oacc[8];
    #pragma unroll
    for (int dg = 0; dg < 8; ++dg) Oacc[dg] = 0.f;
    float llocal = 0.f;
    const int lb = lane * 16;

    // ---- prologue: each group stages its first tile ----
    if (grp < nt) DMA(0, grp);
    __syncthreads();

    int cur = 0;
    #pragma unroll 1
    for (int i = 0; i < IT; ++i) {
        const int t  = grp + i * NGRP;
        const int tn = t + NGRP;
        if (tn < nt) DMA(cur ^ 1, tn);   // T3: issue next, drained at end-of-iter sync

        if (t < nt) {
            const char* ksb = &lds[grp * 32768 + cur * 16384];
            const char* vsb = ksb + 8192;

            // ---- S^T = K * Q^T ----
            f32x4 Sacc[2];
            Sacc[0] = 0.f; Sacc[1] = 0.f;
            __builtin_amdgcn_s_setprio(1);
            #pragma unroll
            for (int s = 0; s < 2; ++s)
                #pragma unroll
                for (int kk = 0; kk < 4; ++kk) {
                    s16x8 kf = *reinterpret_cast<const s16x8*>(ksb + (s * 4 + kk) * 1024 + lb);
                    Sacc[s] = __builtin_amdgcn_mfma_f32_16x16x32_bf16(kf, qf[kk], Sacc[s], 0, 0, 0);
                }
            __builtin_amdgcn_s_setprio(0);

            // ---- valid_length mask (tail tile only) ----
            const int kvrem = vl - t * KVB;
            if (kvrem < KVB) {
                #pragma unroll
                for (int s = 0; s < 2; ++s)
                    #pragma unroll
                    for (int r = 0; r < 4; ++r)
                        if (s * 16 + gl * 4 + r >= kvrem) Sacc[s][r] = -1e30f;
            }

            // ---- fixed-origin softmax numerator ----
            s16x8 pa;
            #pragma unroll
            for (int s = 0; s < 2; ++s)
                #pragma unroll
                for (int r = 0; r < 4; ++r) {
                    const float e = __builtin_amdgcn_exp2f(fminf(Sacc[s][r], 60.f));
                    llocal += e;
                    pa[s * 4 + r] = f2bf(e);
                }

            // ---- O += P * V ----
            __builtin_amdgcn_s_setprio(1);
            #pragma unroll
            for (int dg = 0; dg < 8; ++dg) {
                s16x8 vf = *reinterpret_cast<const s16x8*>(vsb + dg * 1024 + lb);
                Oacc[dg] = __builtin_amdgcn_mfma_f32_16x16x32_bf16(pa, vf, Oacc[dg], 0, 0, 0);
            }
            __builtin_amdgcn_s_setprio(0);
        }

        __syncthreads();   // uniform across all 16 waves; frees buf, drains DMA
        cur ^= 1;
    }

    // ---- merge the 4 kv-groups in LDS (fixed origin: plain sums) ----
    llocal += __shfl_xor(llocal, 16);
    llocal += __shfl_xor(llocal, 32);

    float* red  = (float*)lds;                    // 3 x 32 KB O partials
    float* lred = (float*)&lds[98304];            // 3 x 64 l partials
    if (grp > 0) {
        float* w = red + (size_t)(grp - 1) * 8192 + qslot * 2048;
        #pragma unroll
        for (int dg = 0; dg < 8; ++dg)
            #pragma unroll
            for (int j = 0; j < 4; ++j)
                w[(gl * 4 + j) * 128 + dg * 16 + qi] = Oacc[dg][j];
        if (gl == 0) lred[(grp - 1) * 64 + qslot * 16 + qi] = llocal;
    }
    __syncthreads();

    if (grp == 0) {
        float ltot = llocal;
        #pragma unroll
        for (int g2 = 0; g2 < 3; ++g2) ltot += lred[g2 * 64 + qslot * 16 + qi];
        const float linv = 1.0f / ltot;
        const float l0 = __shfl(linv, gl * 4 + 0);
        const float l1 = __shfl(linv, gl * 4 + 1);
        const float l2 = __shfl(linv, gl * 4 + 2);
        const float l3 = __shfl(linv, gl * 4 + 3);
        float* Ob = O + (size_t)rowbase * DHEAD;
        #pragma unroll
        for (int dg = 0; dg < 8; ++dg) {
            float v0 = Oacc[dg][0], v1 = Oacc[dg][1], v2 = Oacc[dg][2], v3 = Oacc[dg][3];
            #pragma unroll
            for (int g2 = 0; g2 < 3; ++g2) {
                const float* rr = red + (size_t)g2 * 8192 + qslot * 2048;
                v0 += rr[(gl * 4 + 0) * 128 + dg * 16 + qi];
                v1 += rr[(gl * 4 + 1) * 128 + dg * 16 + qi];
                v2 += rr[(gl * 4 + 2) * 128 + dg * 16 + qi];
                v3 += rr[(gl * 4 + 3) * 128 + dg * 16 + qi];
            }
            Ob[(gl * 4 + 0) * DHEAD + dg * 16 + qi] = v0 * l0;
            Ob[(gl * 4 + 1) * DHEAD + dg * 16 + qi] = v1 * l1;
            Ob[(gl * 4 + 2) * DHEAD + dg * 16 + qi] = v2 * l2;
            Ob[(gl * 4 + 3) * DHEAD + dg * 16 + qi] = v3 * l3;
        }
    }
}

extern "C" void kernel_launch(void* const* d_in, const int* in_sizes, int n_in,
                              void* d_out, int out_size, void* d_ws, size_t ws_size,
                              hipStream_t stream) {
    const float* Q  = (const float*)d_in[0];
    const float* K  = (const float*)d_in[1];
    const float* V  = (const float*)d_in[2];
    const int*   VL = (const int*)d_in[3];
    float* O = (float*)d_out;

    const int B = in_sizes[3];
    const int n = in_sizes[0] / (B * DHEAD);
    const int m = in_sizes[1] / (B * DHEAD);
    const int NT = m / KVB;                     // 32

    short* Kz = (short*)d_ws;
    short* Vz = Kz + (size_t)B * NT * (TILB / 2);

    const int nkf = B * NT * 512;               // s16x8 units per tensor
    prep_frag<<<(2 * nkf + 255) / 256, 256, 0, stream>>>(K, V, VL, Kz, Vz, m, NT, nkf);

    // allow 128 KB dynamic LDS (host-side attribute, graph-capture safe)
    hipFuncSetAttribute((const void*)attn_fwd,
                        hipFuncAttributeMaxDynamicSharedMemorySize, LDSZ);
    const int grid = B * (n / BLKQ);
    attn_fwd<<<grid, 1024, LDSZ, stream>>>(Q, Kz, Vz, VL, O, B, n, NT);
}